// Round 9
// baseline (441.150 us; speedup 1.0000x reference)
//
#include <hip/hip_runtime.h>
#include <hip/hip_bf16.h>

#define NN 100000
#define EE 1600000
#define HID 128
#define CLS 40
#define EPSBN 1e-5f
#define NBUK ((NN + 255) >> 8)     // 391 buckets of 256 nodes
#define CAP 6144                   // slots per bucket region
#define EPB 4096                   // edges per p1 block
#define SRCB 13                    // src locality buckets

typedef float f32x4 __attribute__((ext_vector_type(4)));
typedef short s16x8 __attribute__((ext_vector_type(8)));
union U48 { uint4 u; s16x8 s; };

static __device__ __forceinline__ unsigned short f2bf(float f) {
    unsigned u = __float_as_uint(f);
    unsigned r = (u + 0x7fff + ((u >> 16) & 1)) >> 16;   // RNE
    return (unsigned short)r;
}
static __device__ __forceinline__ unsigned pack2(float a, float b) {
    return (unsigned)f2bf(a) | ((unsigned)f2bf(b) << 16);
}
static __device__ __forceinline__ float bflo(unsigned v) { return __uint_as_float(v << 16); }
static __device__ __forceinline__ float bfhi(unsigned v) { return __uint_as_float(v & 0xffff0000u); }

// ---------------- combined init + W pre-pack ----------------

__global__ void prep_all(const float* __restrict__ W1, const float* __restrict__ W2,
                         const float* __restrict__ W3,
                         unsigned* __restrict__ Wf1, unsigned* __restrict__ Wf2,
                         unsigned* __restrict__ Wf3,
                         int* gcur, float* stats1, float* stats2) {
    int blk = blockIdx.x;
    int tid = threadIdx.x;
    if (blk < 64) {
        const float* W = (blk < 32) ? W1 : W2;
        unsigned* Wf = (blk < 32) ? Wf1 : Wf2;
        int t = ((blk & 31) << 8) + tid;
        int q = t & 3, lane = (t >> 2) & 63, f = t >> 8;
        int ks = f >> 3, ct = f & 7;
        int k = ks * 32 + ((lane >> 4) << 3) + q * 2;
        int col = ct * 16 + (lane & 15);
        Wf[t] = pack2(W[k * 128 + col], W[(k + 1) * 128 + col]);
    } else if (blk < 76) {
        int t = ((blk - 64) << 8) + tid;
        int q = t & 3, lane = (t >> 2) & 63, f = t >> 8;
        int ks = f / 3, ct = f - ks * 3;
        int k = ks * 32 + ((lane >> 4) << 3) + q * 2;
        int col = ct * 16 + (lane & 15);
        float v0 = (col < CLS) ? W3[k * CLS + col] : 0.0f;
        float v1 = (col < CLS) ? W3[(k + 1) * CLS + col] : 0.0f;
        Wf3[t] = pack2(v0, v1);
    } else {
        int j = ((blk - 76) << 8) + tid;
        if (j < NBUK) gcur[j] = j * CAP;
        if (blk == 76) {
            stats1[tid] = 0.0f;
            stats2[tid] = 0.0f;
        }
    }
}

// ---------------- CSR build ----------------

__global__ __launch_bounds__(256) void fill_p1_binned(const int* __restrict__ src,
                                                      const int* __restrict__ dst,
                                                      int* gcur, int* __restrict__ tmp) {
    __shared__ int cnt[NBUK];
    __shared__ int base[NBUK];
    int tid = threadIdx.x;
    for (int j = tid; j < NBUK; j += 256) cnt[j] = 0;
    __syncthreads();

    int es[16], ed[16];
    int i0 = blockIdx.x * EPB;
#pragma unroll
    for (int k = 0; k < 16; k++) {
        int i = i0 + k * 256 + tid;
        bool ok = i < EE;
        es[k] = ok ? src[i] : -1;
        ed[k] = ok ? dst[i] : 0;
        if (ok) atomicAdd(&cnt[ed[k] >> 8], 1);
    }
    __syncthreads();
    for (int j = tid; j < NBUK; j += 256) {
        int c = cnt[j];
        base[j] = c ? atomicAdd(&gcur[j], c) : 0;
        cnt[j] = 0;
    }
    __syncthreads();
#pragma unroll
    for (int k = 0; k < 16; k++) {
        if (es[k] >= 0) {
            int b = ed[k] >> 8;
            int r = atomicAdd(&cnt[b], 1);
            tmp[base[b] + r] = (es[k] << 8) | (ed[k] & 255);
        }
    }
}

__global__ __launch_bounds__(512) void bucket_scan(const int* __restrict__ gcur,
                                                   int* __restrict__ gbase,
                                                   int* __restrict__ row_ptr) {
    __shared__ int sc[512];
    int tid = threadIdx.x;
    int v = (tid < NBUK) ? gcur[tid] - tid * CAP : 0;
    sc[tid] = v;
    __syncthreads();
    for (int off = 1; off < 512; off <<= 1) {
        int t = (tid >= off) ? sc[tid - off] : 0;
        __syncthreads();
        sc[tid] += t;
        __syncthreads();
    }
    if (tid < NBUK) gbase[tid] = sc[tid] - v;
    if (tid == NBUK - 1) {
        gbase[NBUK] = sc[tid];
        row_ptr[NN] = sc[tid];
    }
}

__global__ __launch_bounds__(256) void fill_p2a(const int* __restrict__ tmp,
                                                const int* __restrict__ gcur,
                                                const int* __restrict__ gbase,
                                                float* __restrict__ dinv,
                                                int* __restrict__ row_ptr) {
    __shared__ int cnt[256 * SRCB];
    __shared__ int sc[256];
    int b = blockIdx.x;
    int tid = threadIdx.x;
    int total = gcur[b] - b * CAP;
    for (int j = tid; j < 256 * SRCB; j += 256) cnt[j] = 0;
    __syncthreads();
    int lo = b * CAP;
    for (int k = tid; k < total; k += 256) {
        int v = tmp[lo + k];
        int dl = v & 255;
        int s = ((unsigned)v) >> 8;
        atomicAdd(&cnt[dl * SRCB + (s >> 13)], 1);
    }
    __syncthreads();
    int c = 0;
#pragma unroll
    for (int j = 0; j < SRCB; j++) c += cnt[tid * SRCB + j];
    sc[tid] = c;
    __syncthreads();
    for (int off = 1; off < 256; off <<= 1) {
        int t = (tid >= off) ? sc[tid - off] : 0;
        __syncthreads();
        sc[tid] += t;
        __syncthreads();
    }
    int node = (b << 8) + tid;
    if (node < NN) {
        dinv[node] = rsqrtf((float)(c + 1));   // +1 self loop
        row_ptr[node] = gbase[b] + sc[tid] - c;
    }
}

__global__ __launch_bounds__(256) void fill_p2b(const int* __restrict__ tmp,
                                                const int* __restrict__ gcur,
                                                const float* __restrict__ dinv,
                                                const int* __restrict__ row_ptr,
                                                int2* __restrict__ csr) {
    __shared__ int cur[256 * SRCB];
    __shared__ float dlv[256];
    int b = blockIdx.x;
    int tid = threadIdx.x;
    int total = gcur[b] - b * CAP;
    int node = (b << 8) + tid;
    dlv[tid] = (node < NN) ? dinv[node] : 0.0f;
    for (int j = tid; j < 256 * SRCB; j += 256) cur[j] = 0;
    __syncthreads();
    int lo = b * CAP;
    for (int k = tid; k < total; k += 256) {
        int v = tmp[lo + k];
        int dl = v & 255;
        int s = ((unsigned)v) >> 8;
        atomicAdd(&cur[dl * SRCB + (s >> 13)], 1);
    }
    __syncthreads();
    if (node < NN) {
        int base = row_ptr[node];
#pragma unroll
        for (int j = 0; j < SRCB; j++) {
            int t = cur[tid * SRCB + j];
            cur[tid * SRCB + j] = base;
            base += t;
        }
    }
    __syncthreads();
    for (int k = tid; k < total; k += 256) {
        int v = tmp[lo + k];
        int dl = v & 255;
        int s = ((unsigned)v) >> 8;
        int p = atomicAdd(&cur[dl * SRCB + (s >> 13)], 1);
        csr[p] = make_int2(s, __float_as_int(dinv[s] * dlv[dl]));
    }
}

// ---------------- MFMA GEMMs ----------------

template <int MODE>
__global__ __launch_bounds__(256) void gemm128_mfma(const float* __restrict__ Xf,
                                                    const unsigned* __restrict__ Xb,
                                                    const unsigned* __restrict__ Wf,
                                                    const float* __restrict__ scsh,
                                                    const float* __restrict__ xres,
                                                    unsigned* __restrict__ Hb) {
    int t = threadIdx.x;
    int lane = t & 63, w = t >> 6;
    int wr = w >> 1, wc = w & 1;
    int row_base = blockIdx.x * 64 + wr * 32;

    s16x8 b[4][4];
    const uint4* Wv = (const uint4*)Wf;
#pragma unroll
    for (int ks = 0; ks < 4; ks++)
#pragma unroll
        for (int ct = 0; ct < 4; ct++) {
            int f = ks * 8 + wc * 4 + ct;
            U48 u; u.u = Wv[f * 64 + lane];
            b[ks][ct] = u.s;
        }

    f32x4 acc[2][4] = {};
    int lrow = lane & 15;
    int koff = (lane >> 4) << 3;

#pragma unroll
    for (int ks = 0; ks < 4; ks++) {
        int k0 = ks * 32 + koff;
        float sc[8], sh[8];
        if (MODE == 1) {
            float4 s0 = *(const float4*)&scsh[k0];
            float4 s1 = *(const float4*)&scsh[k0 + 4];
            float4 h0 = *(const float4*)&scsh[128 + k0];
            float4 h1 = *(const float4*)&scsh[128 + k0 + 4];
            sc[0]=s0.x; sc[1]=s0.y; sc[2]=s0.z; sc[3]=s0.w;
            sc[4]=s1.x; sc[5]=s1.y; sc[6]=s1.z; sc[7]=s1.w;
            sh[0]=h0.x; sh[1]=h0.y; sh[2]=h0.z; sh[3]=h0.w;
            sh[4]=h1.x; sh[5]=h1.y; sh[6]=h1.z; sh[7]=h1.w;
        }
#pragma unroll
        for (int rf = 0; rf < 2; rf++) {
            int row = row_base + rf * 16 + lrow;
            float v[8];
            if (row < NN) {
                if (MODE == 0) {
                    float4 a0 = *(const float4*)&Xf[(size_t)row * 128 + k0];
                    float4 a1 = *(const float4*)&Xf[(size_t)row * 128 + k0 + 4];
                    v[0]=a0.x; v[1]=a0.y; v[2]=a0.z; v[3]=a0.w;
                    v[4]=a1.x; v[5]=a1.y; v[6]=a1.z; v[7]=a1.w;
                } else {
                    uint4 u = *(const uint4*)&Xb[(size_t)row * 64 + k0 / 2];
                    v[0]=bflo(u.x); v[1]=bfhi(u.x); v[2]=bflo(u.y); v[3]=bfhi(u.y);
                    v[4]=bflo(u.z); v[5]=bfhi(u.z); v[6]=bflo(u.w); v[7]=bfhi(u.w);
                    float4 r0 = *(const float4*)&xres[(size_t)row * 128 + k0];
                    float4 r1 = *(const float4*)&xres[(size_t)row * 128 + k0 + 4];
                    float rr[8] = {r0.x,r0.y,r0.z,r0.w,r1.x,r1.y,r1.z,r1.w};
#pragma unroll
                    for (int j = 0; j < 8; j++)
                        v[j] = fmaxf(fmaf(v[j], sc[j], sh[j]) + rr[j], 0.0f);
                }
            } else {
#pragma unroll
                for (int j = 0; j < 8; j++) v[j] = 0.0f;
            }
            U48 a;
            a.u = make_uint4(pack2(v[0], v[1]), pack2(v[2], v[3]),
                             pack2(v[4], v[5]), pack2(v[6], v[7]));
#pragma unroll
            for (int ct = 0; ct < 4; ct++)
                acc[rf][ct] = __builtin_amdgcn_mfma_f32_16x16x32_bf16(a.s, b[ks][ct], acc[rf][ct], 0, 0, 0);
        }
    }

    unsigned short* Hs = (unsigned short*)Hb;
#pragma unroll
    for (int rf = 0; rf < 2; rf++)
#pragma unroll
        for (int ct = 0; ct < 4; ct++) {
            int col = wc * 64 + ct * 16 + lrow;
            int rbase = row_base + rf * 16 + ((lane >> 4) << 2);
#pragma unroll
            for (int r = 0; r < 4; r++) {
                int row = rbase + r;
                if (row < NN) Hs[(size_t)row * 128 + col] = f2bf(acc[rf][ct][r]);
            }
        }
}

__global__ __launch_bounds__(256) void gemm40_mfma(const unsigned* __restrict__ Xb,
                                                   const unsigned* __restrict__ Wf,
                                                   const float* __restrict__ scsh,
                                                   unsigned* __restrict__ H3) {
    int t = threadIdx.x;
    int lane = t & 63, w = t >> 6;
    int row_base = blockIdx.x * 64 + w * 16;

    s16x8 b[4][3];
    const uint4* Wv = (const uint4*)Wf;
#pragma unroll
    for (int ks = 0; ks < 4; ks++)
#pragma unroll
        for (int ct = 0; ct < 3; ct++) {
            U48 u; u.u = Wv[(ks * 3 + ct) * 64 + lane];
            b[ks][ct] = u.s;
        }

    f32x4 acc[3] = {};
    int lrow = lane & 15;
    int koff = (lane >> 4) << 3;

#pragma unroll
    for (int ks = 0; ks < 4; ks++) {
        int k0 = ks * 32 + koff;
        float4 s0 = *(const float4*)&scsh[k0];
        float4 s1 = *(const float4*)&scsh[k0 + 4];
        float4 h0 = *(const float4*)&scsh[128 + k0];
        float4 h1 = *(const float4*)&scsh[128 + k0 + 4];
        float sc[8] = {s0.x,s0.y,s0.z,s0.w,s1.x,s1.y,s1.z,s1.w};
        float sh[8] = {h0.x,h0.y,h0.z,h0.w,h1.x,h1.y,h1.z,h1.w};
        int row = row_base + lrow;
        float v[8];
        if (row < NN) {
            uint4 u = *(const uint4*)&Xb[(size_t)row * 64 + k0 / 2];
            float av[8] = {bflo(u.x), bfhi(u.x), bflo(u.y), bfhi(u.y),
                           bflo(u.z), bfhi(u.z), bflo(u.w), bfhi(u.w)};
#pragma unroll
            for (int j = 0; j < 8; j++)
                v[j] = fmaxf(fmaf(av[j], sc[j], sh[j]), 0.0f);
        } else {
#pragma unroll
            for (int j = 0; j < 8; j++) v[j] = 0.0f;
        }
        U48 a;
        a.u = make_uint4(pack2(v[0], v[1]), pack2(v[2], v[3]),
                         pack2(v[4], v[5]), pack2(v[6], v[7]));
#pragma unroll
        for (int ct = 0; ct < 3; ct++)
            acc[ct] = __builtin_amdgcn_mfma_f32_16x16x32_bf16(a.s, b[ks][ct], acc[ct], 0, 0, 0);
    }

    unsigned short* Hs = (unsigned short*)H3;
#pragma unroll
    for (int ct = 0; ct < 3; ct++) {
        int col = ct * 16 + lrow;
        if (col >= CLS) continue;
        int rbase = row_base + ((lane >> 4) << 2);
#pragma unroll
        for (int r = 0; r < 4; r++) {
            int row = rbase + r;
            if (row < NN) Hs[(size_t)row * CLS + col] = f2bf(acc[ct][r]);
        }
    }
}

// ---------------- aggregation ----------------

// half-wave per node: lanes 0-31 node n0, lanes 32-63 node n1; lane reads uint2
// (4 features). One gather instruction = 512B covering 2 edges; 8-deep unroll
// = 16 rows in flight. Predicated tail (clamped csr idx, q=0).
__global__ __launch_bounds__(256) void agg128_half(const uint2* __restrict__ h2,
                                                   const int* __restrict__ row_ptr,
                                                   const int2* __restrict__ csr,
                                                   const float* __restrict__ dinv,
                                                   const float* __restrict__ bias,
                                                   uint2* __restrict__ outb) {
    int wid = threadIdx.x >> 6;
    int lane = threadIdx.x & 63;
    int half = lane >> 5, l = lane & 31;
    int node = blockIdx.x * 8 + wid * 2 + half;

    float di = dinv[node];
    float cs = di * di;
    uint2 v = h2[(size_t)node * 32 + l];
    float a0 = bflo(v.x) * cs, a1 = bfhi(v.x) * cs;
    float a2 = bflo(v.y) * cs, a3 = bfhi(v.y) * cs;

    int beg = row_ptr[node], end = row_ptr[node + 1];
    int cnt = end - beg;
    int cmax = max(cnt, __shfl_xor(cnt, 32));

    for (int k = 0; k < cmax; k += 8) {
        int2 p[8];
        float q[8];
        uint2 g[8];
#pragma unroll
        for (int j = 0; j < 8; j++) {
            int idx = beg + k + j;
            int cidx = (idx < EE) ? idx : (EE - 1);
            p[j] = csr[cidx];
            q[j] = (idx < end) ? __int_as_float(p[j].y) : 0.0f;
        }
#pragma unroll
        for (int j = 0; j < 8; j++) g[j] = h2[(size_t)p[j].x * 32 + l];
#pragma unroll
        for (int j = 0; j < 8; j++) {
            a0 = fmaf(bflo(g[j].x), q[j], a0);
            a1 = fmaf(bfhi(g[j].x), q[j], a1);
            a2 = fmaf(bflo(g[j].y), q[j], a2);
            a3 = fmaf(bfhi(g[j].y), q[j], a3);
        }
    }

    float4 b = *(const float4*)&bias[l * 4];
    outb[(size_t)node * 32 + l] =
        make_uint2(pack2(a0 + b.x, a1 + b.y), pack2(a2 + b.z, a3 + b.w));
}

// layer-3: 6 slots × 10 lanes; lane reads uint2 (4 features). One gather = 6 edges.
__global__ __launch_bounds__(256) void agg40_lsm(const uint2* __restrict__ h3,
                                                 const int* __restrict__ row_ptr,
                                                 const int2* __restrict__ csr,
                                                 const float* __restrict__ dinv,
                                                 const float* __restrict__ b3,
                                                 float* __restrict__ out) {
    int wid = threadIdx.x >> 6;
    int lane = threadIdx.x & 63;
    int slot = lane / 10;          // 0..5 (6 = idle lanes 60-63)
    int fp = lane - slot * 10;     // 0..9
    bool sok = slot < 6;
    int node = blockIdx.x * 4 + wid;

    float di = dinv[node];
    float cs = di * di;
    float a0 = 0.0f, a1 = 0.0f, a2 = 0.0f, a3 = 0.0f;
    if (slot == 0) {
        uint2 v = h3[(size_t)node * 10 + fp];
        a0 = bflo(v.x) * cs; a1 = bfhi(v.x) * cs;
        a2 = bflo(v.y) * cs; a3 = bfhi(v.y) * cs;
    }
    int beg = row_ptr[node], end = row_ptr[node + 1];
    int cnt = end - beg;
    for (int k = 0; k < cnt; k += 12) {
#pragma unroll
        for (int jj = 0; jj < 2; jj++) {
            int idx = beg + k + jj * 6 + slot;
            int cidx = (idx < EE) ? idx : (EE - 1);
            int2 p = csr[cidx];
            float q = (sok && idx < end) ? __int_as_float(p.y) : 0.0f;
            uint2 g = h3[(size_t)p.x * 10 + fp];
            a0 = fmaf(bflo(g.x), q, a0); a1 = fmaf(bfhi(g.x), q, a1);
            a2 = fmaf(bflo(g.y), q, a2); a3 = fmaf(bfhi(g.y), q, a3);
        }
    }
    // merge 6 slots -> lanes 0-9
    a0 += __shfl(a0, lane + 30); a1 += __shfl(a1, lane + 30);
    a2 += __shfl(a2, lane + 30); a3 += __shfl(a3, lane + 30);
    float t0 = __shfl(a0, lane + 10), t1 = __shfl(a1, lane + 10);
    float t2 = __shfl(a2, lane + 10), t3 = __shfl(a3, lane + 10);
    float u0 = __shfl(a0, lane + 20), u1 = __shfl(a1, lane + 20);
    float u2 = __shfl(a2, lane + 20), u3 = __shfl(a3, lane + 20);
    bool fin = lane < 10;
    float l0 = 0.0f, l1 = 0.0f, l2 = 0.0f, l3 = 0.0f;
    if (fin) {
        float4 b = *(const float4*)&b3[fp * 4];
        l0 = a0 + t0 + u0 + b.x;
        l1 = a1 + t1 + u1 + b.y;
        l2 = a2 + t2 + u2 + b.z;
        l3 = a3 + t3 + u3 + b.w;
    }
    float m = fin ? fmaxf(fmaxf(l0, l1), fmaxf(l2, l3)) : -1e30f;
#pragma unroll
    for (int off = 32; off > 0; off >>= 1) m = fmaxf(m, __shfl_xor(m, off));
    float s = fin ? (expf(l0 - m) + expf(l1 - m) + expf(l2 - m) + expf(l3 - m)) : 0.0f;
#pragma unroll
    for (int off = 32; off > 0; off >>= 1) s += __shfl_xor(s, off);
    float lse = m + logf(s);
    if (fin)
        *(float4*)&out[(size_t)node * CLS + fp * 4] =
            make_float4(l0 - lse, l1 - lse, l2 - lse, l3 - lse);
}

// ---------------- batchnorm stats (bf16 input) ----------------

__global__ __launch_bounds__(128) void bn_stats(const unsigned* __restrict__ a,
                                                float* __restrict__ stats, int n) {
    int f = threadIdx.x;
    int wrd = f >> 1;
    int hi = f & 1;
    float s = 0.0f, s2 = 0.0f;
    for (int i = blockIdx.x; i < n; i += gridDim.x) {
        unsigned v = a[(size_t)i * 64 + wrd];
        float x = hi ? bfhi(v) : bflo(v);
        s += x;
        s2 = fmaf(x, x, s2);
    }
    atomicAdd(&stats[f], s);
    atomicAdd(&stats[128 + f], s2);
}

__global__ void finalize_scsh(const float* __restrict__ stats, const float* __restrict__ g,
                              const float* __restrict__ be, float* __restrict__ scsh) {
    int f = threadIdx.x;
    float mean = stats[f] * (1.0f / (float)NN);
    float var = stats[128 + f] * (1.0f / (float)NN) - mean * mean;
    float sc = g[f] * rsqrtf(var + EPSBN);
    scsh[f] = sc;
    scsh[128 + f] = be[f] - mean * sc;
}

// ---------------- launcher ----------------

extern "C" void kernel_launch(void* const* d_in, const int* in_sizes, int n_in,
                              void* d_out, int out_size, void* d_ws, size_t ws_size,
                              hipStream_t stream) {
    const float* x   = (const float*)d_in[0];
    const int*   ei  = (const int*)d_in[1];
    const float* W1  = (const float*)d_in[2];
    const float* b1  = (const float*)d_in[3];
    const float* g1  = (const float*)d_in[4];
    const float* be1 = (const float*)d_in[5];
    const float* W2  = (const float*)d_in[6];
    const float* b2  = (const float*)d_in[7];
    const float* g2  = (const float*)d_in[8];
    const float* be2 = (const float*)d_in[9];
    const float* W3  = (const float*)d_in[10];
    const float* b3  = (const float*)d_in[11];
    float* out = (float*)d_out;

    const int* src = ei;
    const int* dst = ei + EE;

    char* w = (char*)d_ws;
    size_t off = 0;
    auto alloc = [&](size_t bytes) {
        void* p = w + off;
        off += (bytes + 255) & ~(size_t)255;
        return p;
    };
    float* dinv      = (float*)alloc((size_t)NN * 4);
    int*   row_ptr   = (int*)alloc((size_t)(NN + 1) * 4);
    int*   gcur      = (int*)alloc((size_t)NBUK * 4);
    int*   gbase     = (int*)alloc((size_t)(NBUK + 1) * 4);
    int*   tmp       = (int*)alloc((size_t)NBUK * CAP * 4);
    int2*  csr       = (int2*)alloc((size_t)EE * 8);
    float* stats1    = (float*)alloc(256 * 4);
    float* stats2    = (float*)alloc(256 * 4);
    float* scsh      = (float*)alloc(256 * 4);
    unsigned* Wf1    = (unsigned*)alloc(8192 * 4);
    unsigned* Wf2    = (unsigned*)alloc(8192 * 4);
    unsigned* Wf3    = (unsigned*)alloc(3072 * 4);
    unsigned* aH     = (unsigned*)alloc((size_t)NN * 64 * 4); // bf16 agg output (post-bias)
    unsigned* hB     = (unsigned*)alloc((size_t)NN * 64 * 4); // bf16 gemm output / gather table
    unsigned* h3     = (unsigned*)alloc((size_t)NN * 20 * 4); // bf16 h3

    const int NB_P1 = (EE + EPB - 1) / EPB;
    const int NB_G  = (NN + 63) / 64;

    // ---- CSR build + weight prep ----
    prep_all<<<78, 256, 0, stream>>>(W1, W2, W3, Wf1, Wf2, Wf3, gcur, stats1, stats2);
    fill_p1_binned<<<NB_P1, 256, 0, stream>>>(src, dst, gcur, tmp);
    bucket_scan<<<1, 512, 0, stream>>>(gcur, gbase, row_ptr);
    fill_p2a<<<NBUK, 256, 0, stream>>>(tmp, gcur, gbase, dinv, row_ptr);
    fill_p2b<<<NBUK, 256, 0, stream>>>(tmp, gcur, dinv, row_ptr, csr);

    // ---- layer 1 ----
    gemm128_mfma<0><<<NB_G, 256, 0, stream>>>(x, nullptr, Wf1, nullptr, nullptr, hB);
    agg128_half<<<NN / 8, 256, 0, stream>>>((const uint2*)hB, row_ptr, csr, dinv, b1, (uint2*)aH);
    bn_stats<<<512, 128, 0, stream>>>(aH, stats1, NN);
    finalize_scsh<<<1, 128, 0, stream>>>(stats1, g1, be1, scsh);

    // ---- layer 2 (BN1 + residual + relu fused into A-fragment load) ----
    gemm128_mfma<1><<<NB_G, 256, 0, stream>>>(nullptr, aH, Wf2, scsh, x, hB);
    agg128_half<<<NN / 8, 256, 0, stream>>>((const uint2*)hB, row_ptr, csr, dinv, b2, (uint2*)aH);
    bn_stats<<<512, 128, 0, stream>>>(aH, stats2, NN);
    finalize_scsh<<<1, 128, 0, stream>>>(stats2, g2, be2, scsh);

    // ---- layer 3 (BN2 + relu fused into A-fragment load) ----
    gemm40_mfma<<<NB_G, 256, 0, stream>>>(aH, Wf3, scsh, h3);
    agg40_lsm<<<NN / 4, 256, 0, stream>>>((const uint2*)h3, row_ptr, csr, dinv, b3, out);
}

// Round 10
// 439.121 us; speedup vs baseline: 1.0046x; 1.0046x over previous
//
#include <hip/hip_runtime.h>
#include <hip/hip_bf16.h>

#define NN 100000
#define EE 1600000
#define HID 128
#define CLS 40
#define EPSBN 1e-5f
#define NBUK ((NN + 255) >> 8)     // 391 buckets of 256 nodes
#define CAP 6144                   // slots per bucket region
#define EPB 4096                   // edges per p1 block
#define SRCB 13                    // src locality buckets

typedef float f32x4 __attribute__((ext_vector_type(4)));
typedef short s16x8 __attribute__((ext_vector_type(8)));
union U48 { uint4 u; s16x8 s; };

static __device__ __forceinline__ unsigned short f2bf(float f) {
    unsigned u = __float_as_uint(f);
    unsigned r = (u + 0x7fff + ((u >> 16) & 1)) >> 16;   // RNE
    return (unsigned short)r;
}
static __device__ __forceinline__ unsigned pack2(float a, float b) {
    return (unsigned)f2bf(a) | ((unsigned)f2bf(b) << 16);
}
static __device__ __forceinline__ float bflo(unsigned v) { return __uint_as_float(v << 16); }
static __device__ __forceinline__ float bfhi(unsigned v) { return __uint_as_float(v & 0xffff0000u); }

// ---------------- combined init + W pre-pack ----------------

__global__ void prep_all(const float* __restrict__ W1, const float* __restrict__ W2,
                         const float* __restrict__ W3,
                         unsigned* __restrict__ Wf1, unsigned* __restrict__ Wf2,
                         unsigned* __restrict__ Wf3,
                         int* gcur, float* stats1, float* stats2) {
    int blk = blockIdx.x;
    int tid = threadIdx.x;
    if (blk < 64) {
        const float* W = (blk < 32) ? W1 : W2;
        unsigned* Wf = (blk < 32) ? Wf1 : Wf2;
        int t = ((blk & 31) << 8) + tid;
        int q = t & 3, lane = (t >> 2) & 63, f = t >> 8;
        int ks = f >> 3, ct = f & 7;
        int k = ks * 32 + ((lane >> 4) << 3) + q * 2;
        int col = ct * 16 + (lane & 15);
        Wf[t] = pack2(W[k * 128 + col], W[(k + 1) * 128 + col]);
    } else if (blk < 76) {
        int t = ((blk - 64) << 8) + tid;
        int q = t & 3, lane = (t >> 2) & 63, f = t >> 8;
        int ks = f / 3, ct = f - ks * 3;
        int k = ks * 32 + ((lane >> 4) << 3) + q * 2;
        int col = ct * 16 + (lane & 15);
        float v0 = (col < CLS) ? W3[k * CLS + col] : 0.0f;
        float v1 = (col < CLS) ? W3[(k + 1) * CLS + col] : 0.0f;
        Wf3[t] = pack2(v0, v1);
    } else {
        int j = ((blk - 76) << 8) + tid;
        if (j < NBUK) gcur[j] = j * CAP;
        if (blk == 76) {
            stats1[tid] = 0.0f;
            stats2[tid] = 0.0f;
        }
    }
}

// ---------------- CSR build ----------------

__global__ __launch_bounds__(256) void fill_p1_binned(const int* __restrict__ src,
                                                      const int* __restrict__ dst,
                                                      int* gcur, int* __restrict__ tmp) {
    __shared__ int cnt[NBUK];
    __shared__ int base[NBUK];
    int tid = threadIdx.x;
    for (int j = tid; j < NBUK; j += 256) cnt[j] = 0;
    __syncthreads();

    int es[16], ed[16];
    int i0 = blockIdx.x * EPB;
#pragma unroll
    for (int k = 0; k < 16; k++) {
        int i = i0 + k * 256 + tid;
        bool ok = i < EE;
        es[k] = ok ? src[i] : -1;
        ed[k] = ok ? dst[i] : 0;
        if (ok) atomicAdd(&cnt[ed[k] >> 8], 1);
    }
    __syncthreads();
    for (int j = tid; j < NBUK; j += 256) {
        int c = cnt[j];
        base[j] = c ? atomicAdd(&gcur[j], c) : 0;
        cnt[j] = 0;
    }
    __syncthreads();
#pragma unroll
    for (int k = 0; k < 16; k++) {
        if (es[k] >= 0) {
            int b = ed[k] >> 8;
            int r = atomicAdd(&cnt[b], 1);
            tmp[base[b] + r] = (es[k] << 8) | (ed[k] & 255);
        }
    }
}

__global__ __launch_bounds__(512) void bucket_scan(const int* __restrict__ gcur,
                                                   int* __restrict__ gbase,
                                                   int* __restrict__ row_ptr) {
    __shared__ int sc[512];
    int tid = threadIdx.x;
    int v = (tid < NBUK) ? gcur[tid] - tid * CAP : 0;
    sc[tid] = v;
    __syncthreads();
    for (int off = 1; off < 512; off <<= 1) {
        int t = (tid >= off) ? sc[tid - off] : 0;
        __syncthreads();
        sc[tid] += t;
        __syncthreads();
    }
    if (tid < NBUK) gbase[tid] = sc[tid] - v;
    if (tid == NBUK - 1) {
        gbase[NBUK] = sc[tid];
        row_ptr[NN] = sc[tid];
    }
}

__global__ __launch_bounds__(256) void fill_p2a(const int* __restrict__ tmp,
                                                const int* __restrict__ gcur,
                                                const int* __restrict__ gbase,
                                                float* __restrict__ dinv,
                                                int* __restrict__ row_ptr) {
    __shared__ int cnt[256 * SRCB];
    __shared__ int sc[256];
    int b = blockIdx.x;
    int tid = threadIdx.x;
    int total = gcur[b] - b * CAP;
    for (int j = tid; j < 256 * SRCB; j += 256) cnt[j] = 0;
    __syncthreads();
    int lo = b * CAP;
    for (int k = tid; k < total; k += 256) {
        int v = tmp[lo + k];
        int dl = v & 255;
        int s = ((unsigned)v) >> 8;
        atomicAdd(&cnt[dl * SRCB + (s >> 13)], 1);
    }
    __syncthreads();
    int c = 0;
#pragma unroll
    for (int j = 0; j < SRCB; j++) c += cnt[tid * SRCB + j];
    sc[tid] = c;
    __syncthreads();
    for (int off = 1; off < 256; off <<= 1) {
        int t = (tid >= off) ? sc[tid - off] : 0;
        __syncthreads();
        sc[tid] += t;
        __syncthreads();
    }
    int node = (b << 8) + tid;
    if (node < NN) {
        dinv[node] = rsqrtf((float)(c + 1));   // +1 self loop
        row_ptr[node] = gbase[b] + sc[tid] - c;
    }
}

__global__ __launch_bounds__(256) void fill_p2b(const int* __restrict__ tmp,
                                                const int* __restrict__ gcur,
                                                const float* __restrict__ dinv,
                                                const int* __restrict__ row_ptr,
                                                int2* __restrict__ csr) {
    __shared__ int cur[256 * SRCB];
    __shared__ float dlv[256];
    int b = blockIdx.x;
    int tid = threadIdx.x;
    int total = gcur[b] - b * CAP;
    int node = (b << 8) + tid;
    dlv[tid] = (node < NN) ? dinv[node] : 0.0f;
    for (int j = tid; j < 256 * SRCB; j += 256) cur[j] = 0;
    __syncthreads();
    int lo = b * CAP;
    for (int k = tid; k < total; k += 256) {
        int v = tmp[lo + k];
        int dl = v & 255;
        int s = ((unsigned)v) >> 8;
        atomicAdd(&cur[dl * SRCB + (s >> 13)], 1);
    }
    __syncthreads();
    if (node < NN) {
        int base = row_ptr[node];
#pragma unroll
        for (int j = 0; j < SRCB; j++) {
            int t = cur[tid * SRCB + j];
            cur[tid * SRCB + j] = base;
            base += t;
        }
    }
    __syncthreads();
    for (int k = tid; k < total; k += 256) {
        int v = tmp[lo + k];
        int dl = v & 255;
        int s = ((unsigned)v) >> 8;
        int p = atomicAdd(&cur[dl * SRCB + (s >> 13)], 1);
        csr[p] = make_int2(s, __float_as_int(dinv[s] * dlv[dl]));
    }
}

// ---------------- MFMA GEMMs ----------------

// MODE 0: A = Xf (fp32). MODE 1: A = relu(bn(Xb bf16) + xres fp32); BN finalize
// computed inline from raw stats (sum, sumsq). Out bf16 H [N][128].
template <int MODE>
__global__ __launch_bounds__(256) void gemm128_mfma(const float* __restrict__ Xf,
                                                    const unsigned* __restrict__ Xb,
                                                    const unsigned* __restrict__ Wf,
                                                    const float* __restrict__ stats,
                                                    const float* __restrict__ gam,
                                                    const float* __restrict__ bet,
                                                    const float* __restrict__ xres,
                                                    unsigned* __restrict__ Hb) {
    int t = threadIdx.x;
    int lane = t & 63, w = t >> 6;
    int wr = w >> 1, wc = w & 1;
    int row_base = blockIdx.x * 64 + wr * 32;

    s16x8 b[4][4];
    const uint4* Wv = (const uint4*)Wf;
#pragma unroll
    for (int ks = 0; ks < 4; ks++)
#pragma unroll
        for (int ct = 0; ct < 4; ct++) {
            int f = ks * 8 + wc * 4 + ct;
            U48 u; u.u = Wv[f * 64 + lane];
            b[ks][ct] = u.s;
        }

    f32x4 acc[2][4] = {};
    int lrow = lane & 15;
    int koff = (lane >> 4) << 3;
    const float invN = 1.0f / (float)NN;

#pragma unroll
    for (int ks = 0; ks < 4; ks++) {
        int k0 = ks * 32 + koff;
        float sc[8], sh[8];
        if (MODE == 1) {
            float4 s0 = *(const float4*)&stats[k0];
            float4 s1 = *(const float4*)&stats[k0 + 4];
            float4 q0 = *(const float4*)&stats[128 + k0];
            float4 q1 = *(const float4*)&stats[128 + k0 + 4];
            float4 g0 = *(const float4*)&gam[k0];
            float4 g1 = *(const float4*)&gam[k0 + 4];
            float4 e0 = *(const float4*)&bet[k0];
            float4 e1 = *(const float4*)&bet[k0 + 4];
            float sv[8] = {s0.x,s0.y,s0.z,s0.w,s1.x,s1.y,s1.z,s1.w};
            float qv[8] = {q0.x,q0.y,q0.z,q0.w,q1.x,q1.y,q1.z,q1.w};
            float gv[8] = {g0.x,g0.y,g0.z,g0.w,g1.x,g1.y,g1.z,g1.w};
            float ev[8] = {e0.x,e0.y,e0.z,e0.w,e1.x,e1.y,e1.z,e1.w};
#pragma unroll
            for (int j = 0; j < 8; j++) {
                float mean = sv[j] * invN;
                float var = qv[j] * invN - mean * mean;
                sc[j] = gv[j] * rsqrtf(var + EPSBN);
                sh[j] = ev[j] - mean * sc[j];
            }
        }
#pragma unroll
        for (int rf = 0; rf < 2; rf++) {
            int row = row_base + rf * 16 + lrow;
            float v[8];
            if (row < NN) {
                if (MODE == 0) {
                    float4 a0 = *(const float4*)&Xf[(size_t)row * 128 + k0];
                    float4 a1 = *(const float4*)&Xf[(size_t)row * 128 + k0 + 4];
                    v[0]=a0.x; v[1]=a0.y; v[2]=a0.z; v[3]=a0.w;
                    v[4]=a1.x; v[5]=a1.y; v[6]=a1.z; v[7]=a1.w;
                } else {
                    uint4 u = *(const uint4*)&Xb[(size_t)row * 64 + k0 / 2];
                    v[0]=bflo(u.x); v[1]=bfhi(u.x); v[2]=bflo(u.y); v[3]=bfhi(u.y);
                    v[4]=bflo(u.z); v[5]=bfhi(u.z); v[6]=bflo(u.w); v[7]=bfhi(u.w);
                    float4 r0 = *(const float4*)&xres[(size_t)row * 128 + k0];
                    float4 r1 = *(const float4*)&xres[(size_t)row * 128 + k0 + 4];
                    float rr[8] = {r0.x,r0.y,r0.z,r0.w,r1.x,r1.y,r1.z,r1.w};
#pragma unroll
                    for (int j = 0; j < 8; j++)
                        v[j] = fmaxf(fmaf(v[j], sc[j], sh[j]) + rr[j], 0.0f);
                }
            } else {
#pragma unroll
                for (int j = 0; j < 8; j++) v[j] = 0.0f;
            }
            U48 a;
            a.u = make_uint4(pack2(v[0], v[1]), pack2(v[2], v[3]),
                             pack2(v[4], v[5]), pack2(v[6], v[7]));
#pragma unroll
            for (int ct = 0; ct < 4; ct++)
                acc[rf][ct] = __builtin_amdgcn_mfma_f32_16x16x32_bf16(a.s, b[ks][ct], acc[rf][ct], 0, 0, 0);
        }
    }

    unsigned short* Hs = (unsigned short*)Hb;
#pragma unroll
    for (int rf = 0; rf < 2; rf++)
#pragma unroll
        for (int ct = 0; ct < 4; ct++) {
            int col = wc * 64 + ct * 16 + lrow;
            int rbase = row_base + rf * 16 + ((lane >> 4) << 2);
#pragma unroll
            for (int r = 0; r < 4; r++) {
                int row = rbase + r;
                if (row < NN) Hs[(size_t)row * 128 + col] = f2bf(acc[rf][ct][r]);
            }
        }
}

// layer-3: A = relu(bn(Xb bf16)) with inline BN finalize, out bf16 [N][40]
__global__ __launch_bounds__(256) void gemm40_mfma(const unsigned* __restrict__ Xb,
                                                   const unsigned* __restrict__ Wf,
                                                   const float* __restrict__ stats,
                                                   const float* __restrict__ gam,
                                                   const float* __restrict__ bet,
                                                   unsigned* __restrict__ H3) {
    int t = threadIdx.x;
    int lane = t & 63, w = t >> 6;
    int row_base = blockIdx.x * 64 + w * 16;

    s16x8 b[4][3];
    const uint4* Wv = (const uint4*)Wf;
#pragma unroll
    for (int ks = 0; ks < 4; ks++)
#pragma unroll
        for (int ct = 0; ct < 3; ct++) {
            U48 u; u.u = Wv[(ks * 3 + ct) * 64 + lane];
            b[ks][ct] = u.s;
        }

    f32x4 acc[3] = {};
    int lrow = lane & 15;
    int koff = (lane >> 4) << 3;
    const float invN = 1.0f / (float)NN;

#pragma unroll
    for (int ks = 0; ks < 4; ks++) {
        int k0 = ks * 32 + koff;
        float4 s0 = *(const float4*)&stats[k0];
        float4 s1 = *(const float4*)&stats[k0 + 4];
        float4 q0 = *(const float4*)&stats[128 + k0];
        float4 q1 = *(const float4*)&stats[128 + k0 + 4];
        float4 g0 = *(const float4*)&gam[k0];
        float4 g1 = *(const float4*)&gam[k0 + 4];
        float4 e0 = *(const float4*)&bet[k0];
        float4 e1 = *(const float4*)&bet[k0 + 4];
        float sv[8] = {s0.x,s0.y,s0.z,s0.w,s1.x,s1.y,s1.z,s1.w};
        float qv[8] = {q0.x,q0.y,q0.z,q0.w,q1.x,q1.y,q1.z,q1.w};
        float gv[8] = {g0.x,g0.y,g0.z,g0.w,g1.x,g1.y,g1.z,g1.w};
        float ev[8] = {e0.x,e0.y,e0.z,e0.w,e1.x,e1.y,e1.z,e1.w};
        float sc[8], sh[8];
#pragma unroll
        for (int j = 0; j < 8; j++) {
            float mean = sv[j] * invN;
            float var = qv[j] * invN - mean * mean;
            sc[j] = gv[j] * rsqrtf(var + EPSBN);
            sh[j] = ev[j] - mean * sc[j];
        }
        int row = row_base + lrow;
        float v[8];
        if (row < NN) {
            uint4 u = *(const uint4*)&Xb[(size_t)row * 64 + k0 / 2];
            float av[8] = {bflo(u.x), bfhi(u.x), bflo(u.y), bfhi(u.y),
                           bflo(u.z), bfhi(u.z), bflo(u.w), bfhi(u.w)};
#pragma unroll
            for (int j = 0; j < 8; j++)
                v[j] = fmaxf(fmaf(av[j], sc[j], sh[j]), 0.0f);
        } else {
#pragma unroll
            for (int j = 0; j < 8; j++) v[j] = 0.0f;
        }
        U48 a;
        a.u = make_uint4(pack2(v[0], v[1]), pack2(v[2], v[3]),
                         pack2(v[4], v[5]), pack2(v[6], v[7]));
#pragma unroll
        for (int ct = 0; ct < 3; ct++)
            acc[ct] = __builtin_amdgcn_mfma_f32_16x16x32_bf16(a.s, b[ks][ct], acc[ct], 0, 0, 0);
    }

    unsigned short* Hs = (unsigned short*)H3;
#pragma unroll
    for (int ct = 0; ct < 3; ct++) {
        int col = ct * 16 + lrow;
        if (col >= CLS) continue;
        int rbase = row_base + ((lane >> 4) << 2);
#pragma unroll
        for (int r = 0; r < 4; r++) {
            int row = rbase + r;
            if (row < NN) Hs[(size_t)row * CLS + col] = f2bf(acc[ct][r]);
        }
    }
}

// ---------------- aggregation ----------------

// half-wave per node, uint2/lane, 12-deep, gathers PREDICATED on idx<end
// (condition uniform per 32-lane half -> exec-masked, no wasted fetches).
__global__ __launch_bounds__(256) void agg128_half(const uint2* __restrict__ h2,
                                                   const int* __restrict__ row_ptr,
                                                   const int2* __restrict__ csr,
                                                   const float* __restrict__ dinv,
                                                   const float* __restrict__ bias,
                                                   uint2* __restrict__ outb) {
    int wid = threadIdx.x >> 6;
    int lane = threadIdx.x & 63;
    int half = lane >> 5, l = lane & 31;
    int node = blockIdx.x * 8 + wid * 2 + half;

    float di = dinv[node];
    float cs = di * di;
    uint2 v = h2[(size_t)node * 32 + l];
    float a0 = bflo(v.x) * cs, a1 = bfhi(v.x) * cs;
    float a2 = bflo(v.y) * cs, a3 = bfhi(v.y) * cs;

    int beg = row_ptr[node], end = row_ptr[node + 1];
    int cnt = end - beg;
    int cmax = max(cnt, __shfl_xor(cnt, 32));

    for (int k = 0; k < cmax; k += 12) {
        int2 p[12];
        float q[12];
        uint2 g[12];
#pragma unroll
        for (int j = 0; j < 12; j++) {
            int idx = beg + k + j;
            bool on = idx < end;
            p[j] = csr[on ? idx : beg];
            q[j] = on ? __int_as_float(p[j].y) : 0.0f;
        }
#pragma unroll
        for (int j = 0; j < 12; j++) {
            int idx = beg + k + j;
            g[j] = (idx < end) ? h2[(size_t)p[j].x * 32 + l] : make_uint2(0u, 0u);
        }
#pragma unroll
        for (int j = 0; j < 12; j++) {
            a0 = fmaf(bflo(g[j].x), q[j], a0);
            a1 = fmaf(bfhi(g[j].x), q[j], a1);
            a2 = fmaf(bflo(g[j].y), q[j], a2);
            a3 = fmaf(bfhi(g[j].y), q[j], a3);
        }
    }

    float4 b = *(const float4*)&bias[l * 4];
    outb[(size_t)node * 32 + l] =
        make_uint2(pack2(a0 + b.x, a1 + b.y), pack2(a2 + b.z, a3 + b.w));
}

// layer-3: 6 slots × 10 lanes; gathers predicated on idx<end (no wasted fetch)
__global__ __launch_bounds__(256) void agg40_lsm(const uint2* __restrict__ h3,
                                                 const int* __restrict__ row_ptr,
                                                 const int2* __restrict__ csr,
                                                 const float* __restrict__ dinv,
                                                 const float* __restrict__ b3,
                                                 float* __restrict__ out) {
    int wid = threadIdx.x >> 6;
    int lane = threadIdx.x & 63;
    int slot = lane / 10;          // 0..5 (6 = idle lanes 60-63)
    int fp = lane - slot * 10;     // 0..9
    bool sok = slot < 6;
    int node = blockIdx.x * 4 + wid;

    float di = dinv[node];
    float cs = di * di;
    float a0 = 0.0f, a1 = 0.0f, a2 = 0.0f, a3 = 0.0f;
    if (slot == 0) {
        uint2 v = h3[(size_t)node * 10 + fp];
        a0 = bflo(v.x) * cs; a1 = bfhi(v.x) * cs;
        a2 = bflo(v.y) * cs; a3 = bfhi(v.y) * cs;
    }
    int beg = row_ptr[node], end = row_ptr[node + 1];
    int cnt = end - beg;
    for (int k = 0; k < cnt; k += 12) {
#pragma unroll
        for (int jj = 0; jj < 2; jj++) {
            int idx = beg + k + jj * 6 + slot;
            bool on = sok && (idx < end);
            int2 p = csr[on ? idx : beg];
            float q = on ? __int_as_float(p.y) : 0.0f;
            uint2 g = on ? h3[(size_t)p.x * 10 + fp] : make_uint2(0u, 0u);
            a0 = fmaf(bflo(g.x), q, a0); a1 = fmaf(bfhi(g.x), q, a1);
            a2 = fmaf(bflo(g.y), q, a2); a3 = fmaf(bfhi(g.y), q, a3);
        }
    }
    // merge 6 slots -> lanes 0-9
    a0 += __shfl(a0, lane + 30); a1 += __shfl(a1, lane + 30);
    a2 += __shfl(a2, lane + 30); a3 += __shfl(a3, lane + 30);
    float t0 = __shfl(a0, lane + 10), t1 = __shfl(a1, lane + 10);
    float t2 = __shfl(a2, lane + 10), t3 = __shfl(a3, lane + 10);
    float u0 = __shfl(a0, lane + 20), u1 = __shfl(a1, lane + 20);
    float u2 = __shfl(a2, lane + 20), u3 = __shfl(a3, lane + 20);
    bool fin = lane < 10;
    float l0 = 0.0f, l1 = 0.0f, l2 = 0.0f, l3 = 0.0f;
    if (fin) {
        float4 b = *(const float4*)&b3[fp * 4];
        l0 = a0 + t0 + u0 + b.x;
        l1 = a1 + t1 + u1 + b.y;
        l2 = a2 + t2 + u2 + b.z;
        l3 = a3 + t3 + u3 + b.w;
    }
    float m = fin ? fmaxf(fmaxf(l0, l1), fmaxf(l2, l3)) : -1e30f;
#pragma unroll
    for (int off = 32; off > 0; off >>= 1) m = fmaxf(m, __shfl_xor(m, off));
    float s = fin ? (expf(l0 - m) + expf(l1 - m) + expf(l2 - m) + expf(l3 - m)) : 0.0f;
#pragma unroll
    for (int off = 32; off > 0; off >>= 1) s += __shfl_xor(s, off);
    float lse = m + logf(s);
    if (fin)
        *(float4*)&out[(size_t)node * CLS + fp * 4] =
            make_float4(l0 - lse, l1 - lse, l2 - lse, l3 - lse);
}

// ---------------- batchnorm stats (bf16 input) ----------------

__global__ __launch_bounds__(128) void bn_stats(const unsigned* __restrict__ a,
                                                float* __restrict__ stats, int n) {
    int f = threadIdx.x;
    int wrd = f >> 1;
    int hi = f & 1;
    float s = 0.0f, s2 = 0.0f;
    for (int i = blockIdx.x; i < n; i += gridDim.x) {
        unsigned v = a[(size_t)i * 64 + wrd];
        float x = hi ? bfhi(v) : bflo(v);
        s += x;
        s2 = fmaf(x, x, s2);
    }
    atomicAdd(&stats[f], s);
    atomicAdd(&stats[128 + f], s2);
}

// ---------------- launcher ----------------

extern "C" void kernel_launch(void* const* d_in, const int* in_sizes, int n_in,
                              void* d_out, int out_size, void* d_ws, size_t ws_size,
                              hipStream_t stream) {
    const float* x   = (const float*)d_in[0];
    const int*   ei  = (const int*)d_in[1];
    const float* W1  = (const float*)d_in[2];
    const float* b1  = (const float*)d_in[3];
    const float* g1  = (const float*)d_in[4];
    const float* be1 = (const float*)d_in[5];
    const float* W2  = (const float*)d_in[6];
    const float* b2  = (const float*)d_in[7];
    const float* g2  = (const float*)d_in[8];
    const float* be2 = (const float*)d_in[9];
    const float* W3  = (const float*)d_in[10];
    const float* b3  = (const float*)d_in[11];
    float* out = (float*)d_out;

    const int* src = ei;
    const int* dst = ei + EE;

    char* w = (char*)d_ws;
    size_t off = 0;
    auto alloc = [&](size_t bytes) {
        void* p = w + off;
        off += (bytes + 255) & ~(size_t)255;
        return p;
    };
    float* dinv      = (float*)alloc((size_t)NN * 4);
    int*   row_ptr   = (int*)alloc((size_t)(NN + 1) * 4);
    int*   gcur      = (int*)alloc((size_t)NBUK * 4);
    int*   gbase     = (int*)alloc((size_t)(NBUK + 1) * 4);
    int*   tmp       = (int*)alloc((size_t)NBUK * CAP * 4);
    int2*  csr       = (int2*)alloc((size_t)EE * 8);
    float* stats1    = (float*)alloc(256 * 4);
    float* stats2    = (float*)alloc(256 * 4);
    unsigned* Wf1    = (unsigned*)alloc(8192 * 4);
    unsigned* Wf2    = (unsigned*)alloc(8192 * 4);
    unsigned* Wf3    = (unsigned*)alloc(3072 * 4);
    unsigned* aH     = (unsigned*)alloc((size_t)NN * 64 * 4); // bf16 agg output (post-bias)
    unsigned* hB     = (unsigned*)alloc((size_t)NN * 64 * 4); // bf16 gemm output / gather table
    unsigned* h3     = (unsigned*)alloc((size_t)NN * 20 * 4); // bf16 h3

    const int NB_P1 = (EE + EPB - 1) / EPB;
    const int NB_G  = (NN + 63) / 64;

    // ---- CSR build + weight prep ----
    prep_all<<<78, 256, 0, stream>>>(W1, W2, W3, Wf1, Wf2, Wf3, gcur, stats1, stats2);
    fill_p1_binned<<<NB_P1, 256, 0, stream>>>(src, dst, gcur, tmp);
    bucket_scan<<<1, 512, 0, stream>>>(gcur, gbase, row_ptr);
    fill_p2a<<<NBUK, 256, 0, stream>>>(tmp, gcur, gbase, dinv, row_ptr);
    fill_p2b<<<NBUK, 256, 0, stream>>>(tmp, gcur, dinv, row_ptr, csr);

    // ---- layer 1 ----
    gemm128_mfma<0><<<NB_G, 256, 0, stream>>>(x, nullptr, Wf1, nullptr, nullptr, nullptr, nullptr, hB);
    agg128_half<<<NN / 8, 256, 0, stream>>>((const uint2*)hB, row_ptr, csr, dinv, b1, (uint2*)aH);
    bn_stats<<<512, 128, 0, stream>>>(aH, stats1, NN);

    // ---- layer 2 (BN1 finalize + residual + relu fused into A-fragment load) ----
    gemm128_mfma<1><<<NB_G, 256, 0, stream>>>(nullptr, aH, Wf2, stats1, g1, be1, x, hB);
    agg128_half<<<NN / 8, 256, 0, stream>>>((const uint2*)hB, row_ptr, csr, dinv, b2, (uint2*)aH);
    bn_stats<<<512, 128, 0, stream>>>(aH, stats2, NN);

    // ---- layer 3 (BN2 finalize + relu fused into A-fragment load) ----
    gemm40_mfma<<<NB_G, 256, 0, stream>>>(aH, Wf3, stats2, g2, be2, h3);
    agg40_lsm<<<NN / 4, 256, 0, stream>>>((const uint2*)h3, row_ptr, csr, dinv, b3, out);
}